// Round 5
// baseline (480.506 us; speedup 1.0000x reference)
//
#include <hip/hip_runtime.h>
#include <math.h>

// Problem constants (fixed shapes from reference)
#define B_   64
#define T_   2048
#define ENC_ 512
#define U_   128
#define NC   16      // K chunks of 32
#define MBLK 64      // rows per block (4 waves x 16 rows)

typedef __attribute__((ext_vector_type(8))) _Float16 half8;
typedef __attribute__((ext_vector_type(4))) float float4v;

// split x into hi (RTN fp16) + lo (fp16 of remainder): combined err ~2^-22|x|
__device__ inline void cvt_split8_f16(const float4 a0, const float4 a1,
                                      half8& h, half8& l) {
    const float xs[8] = {a0.x, a0.y, a0.z, a0.w, a1.x, a1.y, a1.z, a1.w};
#pragma unroll
    for (int j = 0; j < 8; ++j) {
        const _Float16 hi = (_Float16)xs[j];
        h[j] = hi;
        l[j] = (_Float16)(xs[j] - (float)hi);
    }
}

// tanh via single v_exp: 1 - 2/(e^{2x}+1); exact at ±inf, err ~1e-6
__device__ inline float fast_tanh(float x) {
    const float e = __expf(2.0f * x);
    return 1.0f - 2.0f / (e + 1.0f);
}

// ---------------------------------------------------------------------------
// Prep kernel (merged): blocks 0..63 qproj; 64..95 wprep; 96..224 zero.
//  qproj: q'[b][u] = dh[b,:]@Wa[:,u] + ba[u] + bb[u]  (bb folded; bv cancels)
//  wprep: Wb -> MFMA B-frag order, single fp16 (RTN).
//         B-frag (16x16x32): lane L holds B[k=(L>>4)*8+j][n=(L&15)].
//         frag f = c*8+gn; whf[(f*64+L)*8+j]; chunk c = contiguous 8 KB.
//  zero:  uctx (32768) + Zsum (64)
// ---------------------------------------------------------------------------
__global__ __launch_bounds__(256)
void prep_kernel(const float* __restrict__ dh,
                 const float* __restrict__ Wa,
                 const float* __restrict__ ba,
                 const float* __restrict__ bb,
                 const float* __restrict__ Wb,
                 float* __restrict__ q,
                 _Float16* __restrict__ whf,
                 float* __restrict__ uz) {
    const int blk = blockIdx.x;
    const int tid = threadIdx.x;
    if (blk < 64) {
        if (tid < U_) {
            const int b = blk, u = tid;
            const float* dhb = dh + b * ENC_;
            float a0 = 0.f, a1 = 0.f, a2 = 0.f, a3 = 0.f;
#pragma unroll 4
            for (int e = 0; e < ENC_; e += 4) {
                a0 += dhb[e + 0] * Wa[(e + 0) * U_ + u];
                a1 += dhb[e + 1] * Wa[(e + 1) * U_ + u];
                a2 += dhb[e + 2] * Wa[(e + 2) * U_ + u];
                a3 += dhb[e + 3] * Wa[(e + 3) * U_ + u];
            }
            q[b * U_ + u] = ((a0 + a1) + (a2 + a3)) + ba[u] + bb[u];
        }
    } else if (blk < 96) {
        const int fid = (blk - 64) * 4 + (tid >> 6);   // 0..127
        const int c   = fid >> 3;
        const int gn  = fid & 7;
        const int L   = tid & 63;
        const int n   = gn * 16 + (L & 15);
        const int k0  = c * 32 + (L >> 4) * 8;
        half8 hi;
#pragma unroll
        for (int j = 0; j < 8; ++j)
            hi[j] = (_Float16)Wb[(size_t)(k0 + j) * U_ + n];
        *(half8*)(whf + ((size_t)fid * 64 + L) * 8) = hi;
    } else {
        const int i = (blk - 96) * 256 + tid;
        if (i < B_ * ENC_ + B_) uz[i] = 0.f;
    }
}

// ---------------------------------------------------------------------------
// Kernel B v6: fused score GEMM + exp + context. REGISTERS-ONLY, BARRIER-FREE.
// v5 post-mortem: all memory-structure variants land at ~165us with every
// pipe idle (MfmaUtil 8%, VALU 19%, HBM 11%) -> latency-bound with only
// 8 waves/CU (LDS-capped) and barrier/LDS round-trips on the critical path.
// Fix: buy TLP, spend bandwidth.
//  * Wave tile 16 rows x 128 U. The 16x16x32 A-frag layout (lane holds
//    row L&15, k-slice (L>>4)*8..+7) is loaded DIRECTLY from global enc
//    as float4 pairs - per instruction the wave covers 16 rows x 64 B of
//    contiguous, fully-used cache lines. No LDS for A at all.
//  * K in 4 super-chunks of 128: register double-buffer xs[2][8]
//    (static indices under full unroll), prefetch issued one super-chunk
//    (~450 cyc of cvt+MFMA) ahead of use.
//  * B frags read per chunk from L2-resident whf (single-buffer; unrolled
//    loop lets the scheduler hoist loads across MFMA groups).
//  * NO __syncthreads and NO LDS in the whole K-phase; waves are fully
//    independent -> per-wave stalls are hidden by 12 waves/CU
//    (~150 VGPR, launch_bounds(256,3), LDS only ew[64]).
//  * Grid 2048 (64-row blocks), bijective XCD swizzle (2048%8==0): each
//    XCD owns 8 whole batches -> uctx atomics stay intra-XCD.
// Epilogue: tanh*Wv dot over all 128 u in-wave (shfl over 16 lanes),
// e=exp(s) (no max-sub: |s| <= ||Wv||_1 ~ 11, fp32-safe); one barrier.
// Phase 2: block's 64 enc rows (just read -> L2-hot) -> atomicAdd uctx.
// ---------------------------------------------------------------------------
__global__ __launch_bounds__(256, 3)
void score_ctx_kernel(const float* __restrict__ enc,
                      const _Float16* __restrict__ whf,
                      const float* __restrict__ q,
                      const float* __restrict__ Wv,
                      float* __restrict__ expw,
                      float* __restrict__ uctx,
                      float* __restrict__ Zsum) {
    __shared__ float ew[MBLK];

    const int tid = threadIdx.x;
    const int w   = tid >> 6;       // wave 0..3
    const int L   = tid & 63;
    // bijective XCD swizzle: 2048 blocks, 8 XCDs, 256 contiguous per XCD
    const int wg  = ((blockIdx.x & 7) << 8) | (blockIdx.x >> 3);
    const int m0  = wg * MBLK;
    const int b   = m0 >> 11;       // blocks never straddle a batch

    const int n15 = L & 15;
    const int aq  = L >> 4;         // k-quarter 0..3
    // lane's A pointer: row m0 + w*16 + n15, k-slice base aq*8
    const float* aprow = enc + (size_t)(m0 + w * 16 + n15) * ENC_ + aq * 8;

    float4v acc[8];
#pragma unroll
    for (int gi = 0; gi < 8; ++gi) acc[gi] = (float4v)0.f;

    // A super-chunk register double-buffer (static under full unroll):
    // xs[buf][j]: chunk c=j>>1, half j&1 -> floats sc*128 + c*32 + (j&1)*4
    float4 xs[2][8];
#pragma unroll
    for (int j = 0; j < 8; ++j)
        xs[0][j] = *(const float4*)(aprow + (j >> 1) * 32 + (j & 1) * 4);

#pragma unroll
    for (int sc = 0; sc < 4; ++sc) {
        const int cur = sc & 1, nxt = cur ^ 1;
        if (sc < 3) {
#pragma unroll
            for (int j = 0; j < 8; ++j)
                xs[nxt][j] = *(const float4*)(aprow + (sc + 1) * 128 +
                                              (j >> 1) * 32 + (j & 1) * 4);
        }
#pragma unroll
        for (int c = 0; c < 4; ++c) {
            const int cc = sc * 4 + c;
            // B frags: L2-resident, lane-linear 16 B
            half8 bh[8];
#pragma unroll
            for (int gi = 0; gi < 8; ++gi)
                bh[gi] = *(const half8*)(whf + ((size_t)(cc * 8 + gi) * 64 + L) * 8);
            half8 ah, al;
            cvt_split8_f16(xs[cur][2 * c], xs[cur][2 * c + 1], ah, al);
#pragma unroll
            for (int gi = 0; gi < 8; ++gi) {
                acc[gi] = __builtin_amdgcn_mfma_f32_16x16x32_f16(ah, bh[gi], acc[gi], 0, 0, 0);
                acc[gi] = __builtin_amdgcn_mfma_f32_16x16x32_f16(al, bh[gi], acc[gi], 0, 0, 0);
            }
        }
    }

    // ---- epilogue: tanh + Wv dot over all 128 u (in-wave) ----
    // C/D layout: col(u) = gi*16 + n15, row = w*16 + aq*4 + r
    float qv[8], wvv[8];
#pragma unroll
    for (int gi = 0; gi < 8; ++gi) {
        const int u = gi * 16 + n15;
        qv[gi]  = q[b * U_ + u];
        wvv[gi] = Wv[u];
    }
#pragma unroll
    for (int r = 0; r < 4; ++r) {
        float s = 0.f;
#pragma unroll
        for (int gi = 0; gi < 8; ++gi)
            s += fast_tanh(qv[gi] + acc[gi][r]) * wvv[gi];
        s += __shfl_xor(s, 1, 64);
        s += __shfl_xor(s, 2, 64);
        s += __shfl_xor(s, 4, 64);
        s += __shfl_xor(s, 8, 64);
        if (n15 == 0) {
            const int row = w * 16 + aq * 4 + r;
            const float e = __expf(s);
            ew[row] = e;
            expw[m0 + row] = e;
        }
    }
    __syncthreads();

    // ---- phase 2: unnormalized context over this block's 64 rows ----
    const int col = tid * 2;
    const float* ebase = enc + (size_t)m0 * ENC_ + col;
    float sx = 0.f, sy = 0.f;
#pragma unroll 8
    for (int t = 0; t < MBLK; ++t) {
        const float wgt = ew[t];                       // LDS broadcast
        const float2 v = *(const float2*)(ebase + (size_t)t * ENC_);
        sx += wgt * v.x;
        sy += wgt * v.y;
    }
    atomicAdd(&uctx[b * ENC_ + col], sx);
    atomicAdd(&uctx[b * ENC_ + col + 1], sy);

    if (tid < MBLK) {
        float z = ew[tid];
        z += __shfl_xor(z, 1, 64);
        z += __shfl_xor(z, 2, 64);
        z += __shfl_xor(z, 4, 64);
        z += __shfl_xor(z, 8, 64);
        z += __shfl_xor(z, 16, 64);
        z += __shfl_xor(z, 32, 64);
        if (tid == 0) atomicAdd(&Zsum[b], z);
    }
}

// ---------------------------------------------------------------------------
// Kernel N: normalize — ctx = uctx/Z, attn = expw/Z.
// ---------------------------------------------------------------------------
__global__ void normalize_kernel(const float* __restrict__ uctx,
                                 const float* __restrict__ Zsum,
                                 const float* __restrict__ expw,
                                 float* __restrict__ ctx,
                                 float* __restrict__ attn) {
    const int idx = blockIdx.x * 256 + threadIdx.x;
    if (idx < B_ * ENC_) {
        ctx[idx] = uctx[idx] / Zsum[idx >> 9];        // ENC_ = 512
    } else {
        const int i2 = idx - B_ * ENC_;
        attn[i2] = expw[i2] / Zsum[i2 >> 11];         // T_ = 2048
    }
}

// ---------------------------------------------------------------------------
extern "C" void kernel_launch(void* const* d_in, const int* in_sizes, int n_in,
                              void* d_out, int out_size, void* d_ws, size_t ws_size,
                              hipStream_t stream) {
    const float* dh  = (const float*)d_in[0];  // [64,512]
    const float* enc = (const float*)d_in[1];  // [64,2048,512]
    const float* Wa  = (const float*)d_in[2];  // [512,128]
    const float* ba  = (const float*)d_in[3];  // [128]
    const float* Wb  = (const float*)d_in[4];  // [512,128]
    const float* bb  = (const float*)d_in[5];  // [128]
    const float* Wv  = (const float*)d_in[6];  // [128,1]
    // d_in[7] = bv — cancels in softmax, unused.

    float* out      = (float*)d_out;
    float* ctx      = out;                 // [64,512]
    float* attn_out = out + (B_ * ENC_);   // [64,2048]

    float* ws   = (float*)d_ws;
    float* q    = ws;                              // 8192
    float* expw = ws + 8192;                       // 131072
    float* uctx = ws + 8192 + B_ * T_;             // 32768
    float* Zs   = uctx + B_ * ENC_;                // 64
    _Float16* whf = (_Float16*)(Zs + 64);          // 65536 halfs (128 KB)

    prep_kernel<<<225, 256, 0, stream>>>(dh, Wa, ba, bb, Wb, q, whf, uctx);
    score_ctx_kernel<<<(B_ * T_) / MBLK, 256, 0, stream>>>(enc, whf, q, Wv,
                                                           expw, uctx, Zs);
    normalize_kernel<<<(B_ * (ENC_ + T_)) / 256, 256, 0, stream>>>(uctx, Zs, expw,
                                                                   ctx, attn_out);
}